// Round 6
// baseline (305.578 us; speedup 1.0000x reference)
//
#include <hip/hip_runtime.h>
#include <stdint.h>

#define BB   8
#define NN   2048
#define FIN  256
#define FOUT 128

using short8 = __attribute__((ext_vector_type(8))) short;
using f32x4  = __attribute__((ext_vector_type(4))) float;

__device__ __forceinline__ unsigned short rbf(float f) {
    return (unsigned short)((__float_as_uint(f) + 0x8000u) >> 16);
}

// Calibration: 2 probe MFMAs read off the true (row,col) label of each
// accumulator element (validated round 4). Epilogues index by these labels.
__device__ __forceinline__ void mfma_calib(int m, int quad, int* Mlab, int* Nlab) {
    short8 pa1, pb1, pa2, pb2;
    const short one = (short)0x3F80;            // bf16 1.0
    const short mb  = (short)rbf((float)m);     // bf16 m (exact, m<16)
#pragma unroll
    for (int j = 0; j < 8; ++j) { pa1[j] = 0; pa2[j] = 0; pb1[j] = mb; pb2[j] = one; }
    if (quad == 0) { pa1[0] = one; pa2[0] = mb; }
    f32x4 zz = {0.f, 0.f, 0.f, 0.f};
    f32x4 c1 = __builtin_amdgcn_mfma_f32_16x16x32_bf16(pa1, pb1, zz, 0, 0, 0);
    f32x4 c2 = __builtin_amdgcn_mfma_f32_16x16x32_bf16(pa2, pb2, zz, 0, 0, 0);
#pragma unroll
    for (int r = 0; r < 4; ++r) {
        Nlab[r] = ((int)c1[r]) & 15;
        Mlab[r] = ((int)c2[r]) & 15;
    }
}

// ---------------- W[256][128] fp32 -> wt[128][256] bf16 (W^T) --------------
__global__ __launch_bounds__(256) void gat_wt(const float* __restrict__ W,
                                              unsigned short* __restrict__ wt) {
    const int g  = blockIdx.x * 256 + threadIdx.x;
    const int k  = g >> 5;
    const int o4 = (g & 31) << 2;
    float4 wv = *(const float4*)(W + (k << 7) + o4);
    wt[((o4 + 0) << 8) + k] = rbf(wv.x);
    wt[((o4 + 1) << 8) + k] = rbf(wv.y);
    wt[((o4 + 2) << 8) + k] = rbf(wv.z);
    wt[((o4 + 3) << 8) + k] = rbf(wv.w);
}

// ---------------- stage 1: h = x@W via MFMA (16 rows/block, 1024 blocks) ---
// x cooperatively staged to LDS in 1KB-contiguous bursts; MFMA A-frags from
// LDS; f1/f2 fp32 + ht[b][o][i] bf16 epilogue via calibrated labels.
__global__ __launch_bounds__(256) void gat_h3(
        const float* __restrict__ x, const unsigned short* __restrict__ wt,
        const float* __restrict__ a, unsigned short* __restrict__ ht,
        float* __restrict__ f1, float* __restrict__ f2) {
    __shared__ unsigned short xs[16][264];
    __shared__ float hs[16][132];
    const int bk   = blockIdx.x;
    const int R0   = bk << 4;
    const int b    = R0 >> 11;
    const int il0  = R0 & (NN - 1);
    const int tid  = threadIdx.x;
    const int w    = tid >> 6;
    const int lane = tid & 63;
    const int m    = lane & 15;
    const int quad = lane >> 4;

    // stage x: wave w loads rows 4w..4w+3; each instr = 64 lanes x 16B = 1KB burst
#pragma unroll
    for (int rr = 0; rr < 4; ++rr) {
        const int row = (w << 2) + rr;
        float4 xv = *(const float4*)(x + (size_t)(R0 + row) * FIN + (lane << 2));
        ushort4 c4;
        c4.x = rbf(xv.x); c4.y = rbf(xv.y); c4.z = rbf(xv.z); c4.w = rbf(xv.w);
        *(ushort4*)(&xs[row][lane << 2]) = c4;
    }
    int Mlab[4], Nlab[4];
    mfma_calib(m, quad, Mlab, Nlab);
    __syncthreads();

    f32x4 zz = {0.f, 0.f, 0.f, 0.f};
    f32x4 acc[2] = {zz, zz};
#pragma unroll
    for (int kc = 0; kc < 8; ++kc) {
        const int k0 = (kc << 5) + (quad << 3);
        short8 av = *(const short8*)(&xs[m][k0]);
#pragma unroll
        for (int t = 0; t < 2; ++t) {
            const int ot = (w << 1) + t;
            short8 bw = *(const short8*)(wt + (((ot << 4) + m) << 8) + k0);
            acc[t] = __builtin_amdgcn_mfma_f32_16x16x32_bf16(av, bw, acc[t], 0, 0, 0);
        }
    }
#pragma unroll
    for (int t = 0; t < 2; ++t)
#pragma unroll
        for (int r = 0; r < 4; ++r)
            hs[Mlab[r]][(((w << 1) + t) << 4) + Nlab[r]] = acc[t][r];
    __syncthreads();

    // f1/f2 (fp32)
    {
        const int i   = tid >> 4;
        const int seg = tid & 15;
        const int o0  = seg << 3;
        float s1 = 0.f, s2 = 0.f;
#pragma unroll
        for (int e = 0; e < 8; ++e) {
            float hv = hs[i][o0 + e];
            s1 = fmaf(hv, a[o0 + e], s1);
            s2 = fmaf(hv, a[FOUT + o0 + e], s2);
        }
        s1 += __shfl_xor(s1, 1); s1 += __shfl_xor(s1, 2);
        s1 += __shfl_xor(s1, 4); s1 += __shfl_xor(s1, 8);
        s2 += __shfl_xor(s2, 1); s2 += __shfl_xor(s2, 2);
        s2 += __shfl_xor(s2, 4); s2 += __shfl_xor(s2, 8);
        if (seg == 0) { f1[R0 + i] = s1; f2[R0 + i] = s2; }
    }
    // ht[b][o][i] bf16
    {
        const int o  = tid >> 1;
        const int i8 = (tid & 1) << 3;
        short8 hv;
#pragma unroll
        for (int e = 0; e < 8; ++e) hv[e] = (short)rbf(hs[i8 + e][o]);
        *(short8*)(ht + ((size_t)((b << 7) + o) << 11) + il0 + i8) = hv;
    }
}

// ---------------- stage 2: fused masked-softmax attention ------------------
// Per 256-j chunk: cooperative adj load (1KB contiguous per instr), exp on
// coalesced data, bf16 P-tile in LDS (double-buffered); MFMA consumes P from
// LDS vs L2-resident ht. accbuf overlays the P-tile region (33KB total).
__global__ __launch_bounds__(256, 4) void gat_s3(
        const int* __restrict__ adj, const unsigned short* __restrict__ ht,
        const float* __restrict__ f1, const float* __restrict__ f2,
        float* __restrict__ out) {
    alignas(16) __shared__ char smem[32832];
    unsigned short* P = (unsigned short*)smem;                 // 2 x [16][264] bf16
    float (*accbuf)[16][128] = (float (*)[16][128])smem;       // overlay, used post-loop
    float* sred = (float*)(smem + 32768);                      // [16]

    const int bk   = blockIdx.x;        // 0..1023
    const int b    = bk & 7;            // batch fastest -> per-XCD L2 locality
    const int i0   = (bk >> 3) << 4;
    const int tid  = threadIdx.x;
    const int w    = tid >> 6;
    const int lane = tid & 63;
    const int m    = lane & 15;
    const int quad = lane >> 4;

    int Mlab[4], Nlab[4];
    mfma_calib(m, quad, Mlab, Nlab);

    const int*   adjb = adj + ((size_t)((b << 11) + i0) << 11);
    const float* f2b  = f2 + (b << 11);
    const unsigned short* htb = ht + ((size_t)b << 18);

    float f1v[4];
#pragma unroll
    for (int rr = 0; rr < 4; ++rr) f1v[rr] = f1[(b << 11) + i0 + (w << 2) + rr];

    f32x4 zz = {0.f, 0.f, 0.f, 0.f};
    f32x4 acc[8];
#pragma unroll
    for (int t = 0; t < 8; ++t) acc[t] = zz;
    float sp[4] = {0.f, 0.f, 0.f, 0.f};

    // ---- producer: chunk C (256 j) into buffer bb ----
    auto produce = [&](int C, int bb) {
        float4 fj = *(const float4*)(f2b + C + (lane << 2));
        float fv[4] = {fj.x, fj.y, fj.z, fj.w};
#pragma unroll
        for (int rr = 0; rr < 4; ++rr) {
            const int row = (w << 2) + rr;
            int4 av = *(const int4*)(adjb + ((size_t)row << 11) + C + (lane << 2));
            int am[4] = {av.x, av.y, av.z, av.w};
            const float f1r = f1v[rr];
            ushort4 pk;
            unsigned short* pkp = (unsigned short*)&pk;
#pragma unroll
            for (int u = 0; u < 4; ++u) {
                float e = f1r + fv[u];
                float p = (am[u] > 0) ? __expf(fmaxf(e, 0.2f * e)) : 0.f;
                sp[rr] += p;
                pkp[u] = rbf(p);
            }
            *(ushort4*)(P + bb * 4224 + row * 264 + (lane << 2)) = pk;
        }
    };
    // ---- consumer: MFMA chunk C from buffer bb ----
    auto consume = [&](int C, int bb) {
#pragma unroll
        for (int t = 0; t < 2; ++t) {
            const int jl = (((w << 1) + t) << 5) + (quad << 3);
            short8 pa = *(const short8*)(P + bb * 4224 + m * 264 + jl);
#pragma unroll
            for (int ot = 0; ot < 8; ++ot) {
                short8 hf = *(const short8*)(htb + ((size_t)((ot << 4) + m) << 11) + C + jl);
                acc[ot] = __builtin_amdgcn_mfma_f32_16x16x32_bf16(pa, hf, acc[ot], 0, 0, 0);
            }
        }
    };

    produce(0, 0);
#pragma unroll
    for (int c = 0; c < 8; ++c) {
        __syncthreads();
        if (c < 7) produce((c + 1) << 8, (c + 1) & 1);
        consume(c << 8, c & 1);
    }
    __syncthreads();   // P-tile dead; accbuf overlay safe from here

    // row sums: all 64 lanes hold partials of row 4w+rr
#pragma unroll
    for (int rr = 0; rr < 4; ++rr) {
        float v = sp[rr];
        v += __shfl_xor(v, 1);  v += __shfl_xor(v, 2);
        v += __shfl_xor(v, 4);  v += __shfl_xor(v, 8);
        v += __shfl_xor(v, 16); v += __shfl_xor(v, 32);
        if (lane == 0) sred[(w << 2) + rr] = v;
    }
#pragma unroll
    for (int ot = 0; ot < 8; ++ot)
#pragma unroll
        for (int r = 0; r < 4; ++r)
            accbuf[w][Mlab[r]][(ot << 4) + Nlab[r]] = acc[ot][r];
    __syncthreads();

    {
        const int row = tid >> 4;
        const int o0  = (tid & 15) << 3;
        const float inv = 1.0f / sred[row];
        float v[8];
#pragma unroll
        for (int d = 0; d < 8; ++d)
            v[d] = (accbuf[0][row][o0 + d] + accbuf[1][row][o0 + d]) +
                   (accbuf[2][row][o0 + d] + accbuf[3][row][o0 + d]);
        float4 r0, r1;
        float y;
        y = v[0] * inv; r0.x = y > 0.f ? y : expm1f(y);
        y = v[1] * inv; r0.y = y > 0.f ? y : expm1f(y);
        y = v[2] * inv; r0.z = y > 0.f ? y : expm1f(y);
        y = v[3] * inv; r0.w = y > 0.f ? y : expm1f(y);
        y = v[4] * inv; r1.x = y > 0.f ? y : expm1f(y);
        y = v[5] * inv; r1.y = y > 0.f ? y : expm1f(y);
        y = v[6] * inv; r1.z = y > 0.f ? y : expm1f(y);
        y = v[7] * inv; r1.w = y > 0.f ? y : expm1f(y);
        float* orow = out + (((size_t)(b << 11) + i0 + row) << 7) + o0;
        *(float4*)(orow)     = r0;
        *(float4*)(orow + 4) = r1;
    }
}

extern "C" void kernel_launch(void* const* d_in, const int* in_sizes, int n_in,
                              void* d_out, int out_size, void* d_ws, size_t ws_size,
                              hipStream_t stream) {
    const float* x   = nullptr;
    const int*   adj = nullptr;
    const float* W   = nullptr;
    const float* a   = nullptr;
    for (int i = 0; i < n_in; ++i) {
        const long s = in_sizes[i];
        if      (s == (long)BB * NN * NN)  adj = (const int*)d_in[i];
        else if (s == (long)BB * NN * FIN) x   = (const float*)d_in[i];
        else if (s == (long)FIN * FOUT)    W   = (const float*)d_in[i];
        else if (s == 2L * FOUT)           a   = (const float*)d_in[i];
    }
    if (!x)   x   = (const float*)d_in[0];
    if (!adj) adj = (const int*)d_in[1];
    if (!W)   W   = (const float*)d_in[2];
    if (!a)   a   = (const float*)d_in[3];
    float* out = (float*)d_out;

    unsigned short* wt = (unsigned short*)d_ws;            // 64 KB  W^T bf16
    unsigned short* ht = wt + 32768;                       // 4 MB   h^T bf16 [B][128][N]
    float* f1 = (float*)(ht + (size_t)BB * NN * FOUT);     // 64 KB
    float* f2 = f1 + BB * NN;                              // 64 KB

    hipLaunchKernelGGL(gat_wt, dim3(32),   dim3(256), 0, stream, W, wt);
    hipLaunchKernelGGL(gat_h3, dim3(1024), dim3(256), 0, stream, x, wt, a, ht, f1, f2);
    hipLaunchKernelGGL(gat_s3, dim3(1024), dim3(256), 0, stream, adj, ht, f1, f2, out);
}

// Round 7
// 246.988 us; speedup vs baseline: 1.2372x; 1.2372x over previous
//
#include <hip/hip_runtime.h>
#include <stdint.h>

#define BB   8
#define NN   2048
#define FIN  256
#define FOUT 128

using short8 = __attribute__((ext_vector_type(8))) short;
using f32x4  = __attribute__((ext_vector_type(4))) float;

__device__ __forceinline__ unsigned short rbf(float f) {
    return (unsigned short)((__float_as_uint(f) + 0x8000u) >> 16);
}

// Calibration: 2 probe MFMAs read off the true (row,col) label of each
// accumulator element (validated round 4). Epilogues index by these labels.
__device__ __forceinline__ void mfma_calib(int m, int quad, int* Mlab, int* Nlab) {
    short8 pa1, pb1, pa2, pb2;
    const short one = (short)0x3F80;            // bf16 1.0
    const short mb  = (short)rbf((float)m);     // bf16 m (exact, m<16)
#pragma unroll
    for (int j = 0; j < 8; ++j) { pa1[j] = 0; pa2[j] = 0; pb1[j] = mb; pb2[j] = one; }
    if (quad == 0) { pa1[0] = one; pa2[0] = mb; }
    f32x4 zz = {0.f, 0.f, 0.f, 0.f};
    f32x4 c1 = __builtin_amdgcn_mfma_f32_16x16x32_bf16(pa1, pb1, zz, 0, 0, 0);
    f32x4 c2 = __builtin_amdgcn_mfma_f32_16x16x32_bf16(pa2, pb2, zz, 0, 0, 0);
#pragma unroll
    for (int r = 0; r < 4; ++r) {
        Nlab[r] = ((int)c1[r]) & 15;
        Mlab[r] = ((int)c2[r]) & 15;
    }
}

// ---------------- W[256][128] fp32 -> wt[128][256] bf16 (W^T) --------------
__global__ __launch_bounds__(256) void gat_wt(const float* __restrict__ W,
                                              unsigned short* __restrict__ wt) {
    const int g  = blockIdx.x * 256 + threadIdx.x;
    const int k  = g >> 5;
    const int o4 = (g & 31) << 2;
    float4 wv = *(const float4*)(W + (k << 7) + o4);
    wt[((o4 + 0) << 8) + k] = rbf(wv.x);
    wt[((o4 + 1) << 8) + k] = rbf(wv.y);
    wt[((o4 + 2) << 8) + k] = rbf(wv.z);
    wt[((o4 + 3) << 8) + k] = rbf(wv.w);
}

// ---------------- stage 1: h = x@W via MFMA (16 rows/block, 1024 blocks) ---
// Unchanged from round 6 (passed; not in top-5 dispatches => cheap).
__global__ __launch_bounds__(256) void gat_h3(
        const float* __restrict__ x, const unsigned short* __restrict__ wt,
        const float* __restrict__ a, unsigned short* __restrict__ ht,
        float* __restrict__ f1, float* __restrict__ f2) {
    __shared__ unsigned short xs[16][264];
    __shared__ float hs[16][132];
    const int bk   = blockIdx.x;
    const int R0   = bk << 4;
    const int b    = R0 >> 11;
    const int il0  = R0 & (NN - 1);
    const int tid  = threadIdx.x;
    const int w    = tid >> 6;
    const int lane = tid & 63;
    const int m    = lane & 15;
    const int quad = lane >> 4;

#pragma unroll
    for (int rr = 0; rr < 4; ++rr) {
        const int row = (w << 2) + rr;
        float4 xv = *(const float4*)(x + (size_t)(R0 + row) * FIN + (lane << 2));
        ushort4 c4;
        c4.x = rbf(xv.x); c4.y = rbf(xv.y); c4.z = rbf(xv.z); c4.w = rbf(xv.w);
        *(ushort4*)(&xs[row][lane << 2]) = c4;
    }
    int Mlab[4], Nlab[4];
    mfma_calib(m, quad, Mlab, Nlab);
    __syncthreads();

    f32x4 zz = {0.f, 0.f, 0.f, 0.f};
    f32x4 acc[2] = {zz, zz};
#pragma unroll
    for (int kc = 0; kc < 8; ++kc) {
        const int k0 = (kc << 5) + (quad << 3);
        short8 av = *(const short8*)(&xs[m][k0]);
#pragma unroll
        for (int t = 0; t < 2; ++t) {
            const int ot = (w << 1) + t;
            short8 bw = *(const short8*)(wt + (((ot << 4) + m) << 8) + k0);
            acc[t] = __builtin_amdgcn_mfma_f32_16x16x32_bf16(av, bw, acc[t], 0, 0, 0);
        }
    }
#pragma unroll
    for (int t = 0; t < 2; ++t)
#pragma unroll
        for (int r = 0; r < 4; ++r)
            hs[Mlab[r]][(((w << 1) + t) << 4) + Nlab[r]] = acc[t][r];
    __syncthreads();

    {
        const int i   = tid >> 4;
        const int seg = tid & 15;
        const int o0  = seg << 3;
        float s1 = 0.f, s2 = 0.f;
#pragma unroll
        for (int e = 0; e < 8; ++e) {
            float hv = hs[i][o0 + e];
            s1 = fmaf(hv, a[o0 + e], s1);
            s2 = fmaf(hv, a[FOUT + o0 + e], s2);
        }
        s1 += __shfl_xor(s1, 1); s1 += __shfl_xor(s1, 2);
        s1 += __shfl_xor(s1, 4); s1 += __shfl_xor(s1, 8);
        s2 += __shfl_xor(s2, 1); s2 += __shfl_xor(s2, 2);
        s2 += __shfl_xor(s2, 4); s2 += __shfl_xor(s2, 8);
        if (seg == 0) { f1[R0 + i] = s1; f2[R0 + i] = s2; }
    }
    {
        const int o  = tid >> 1;
        const int i8 = (tid & 1) << 3;
        short8 hv;
#pragma unroll
        for (int e = 0; e < 8; ++e) hv[e] = (short)rbf(hs[i8 + e][o]);
        *(short8*)(ht + ((size_t)((b << 7) + o) << 11) + il0 + i8) = hv;
    }
}

// ---------------- stage 2: fused masked-softmax attention ------------------
// Barrier-free j-loop (R4 skeleton). Block = 32 rows; wave = one j-quarter
// with TWO P fragments (rows m and m+16) sharing the same hf B-fragments ->
// ht re-read bytes halved vs R4. Epilogue: 2-phase LDS combine.
__global__ __launch_bounds__(256, 2) void gat_s4(
        const int* __restrict__ adj, const unsigned short* __restrict__ ht,
        const float* __restrict__ f1, const float* __restrict__ f2,
        float* __restrict__ out) {
    const int bk   = blockIdx.x;        // 0..511
    const int b    = bk & 7;            // batch fastest -> per-XCD L2 locality
    const int i0   = (bk >> 3) << 5;    // 32 rows per block
    const int tid  = threadIdx.x;
    const int w    = tid >> 6;          // j-quarter
    const int lane = tid & 63;
    const int m    = lane & 15;
    const int quad = lane >> 4;

    __shared__ float accb[2][32][128];  // 32 KB (used only after the j-loop)
    __shared__ float sbuf[4][2][16];

    int Mlab[4], Nlab[4];
    mfma_calib(m, quad, Mlab, Nlab);

    const int gi0 = (b << 11) + i0;
    const float f1a = f1[gi0 + m];
    const float f1b = f1[gi0 + 16 + m];
    const int* adjr0 = adj + ((size_t)(gi0 + m) << 11);
    const int* adjr1 = adj + ((size_t)(gi0 + 16 + m) << 11);
    const float* f2b = f2 + (b << 11);
    const unsigned short* htb = ht + ((size_t)b << 18);

    f32x4 zz = {0.f, 0.f, 0.f, 0.f};
    f32x4 acc1[8], acc2[8];
#pragma unroll
    for (int t = 0; t < 8; ++t) { acc1[t] = zz; acc2[t] = zz; }
    float s1 = 0.f, s2 = 0.f;

    const int jb = (w << 9) + (quad << 3);
#pragma unroll 2
    for (int c = 0; c < 16; ++c) {
        const int j0 = jb + (c << 5);
        short8 hf[8];
#pragma unroll
        for (int ot = 0; ot < 8; ++ot)
            hf[ot] = *(const short8*)(htb + ((size_t)((ot << 4) + m) << 11) + j0);

        int4   aA0 = *(const int4*)(adjr0 + j0);
        int4   aA1 = *(const int4*)(adjr0 + j0 + 4);
        int4   aB0 = *(const int4*)(adjr1 + j0);
        int4   aB1 = *(const int4*)(adjr1 + j0 + 4);
        float4 fa  = *(const float4*)(f2b + j0);
        float4 fb  = *(const float4*)(f2b + j0 + 4);
        float fm[8] = {fa.x, fa.y, fa.z, fa.w, fb.x, fb.y, fb.z, fb.w};

        float pA[8], pB[8];
        {
            int am[8] = {aA0.x, aA0.y, aA0.z, aA0.w, aA1.x, aA1.y, aA1.z, aA1.w};
#pragma unroll
            for (int u = 0; u < 8; ++u) {
                float e = f1a + fm[u];
                pA[u] = (am[u] > 0) ? __expf(fmaxf(e, 0.2f * e)) : 0.f;
            }
        }
        {
            int bm[8] = {aB0.x, aB0.y, aB0.z, aB0.w, aB1.x, aB1.y, aB1.z, aB1.w};
#pragma unroll
            for (int u = 0; u < 8; ++u) {
                float e = f1b + fm[u];
                pB[u] = (bm[u] > 0) ? __expf(fmaxf(e, 0.2f * e)) : 0.f;
            }
        }
        s1 += ((pA[0] + pA[1]) + (pA[2] + pA[3])) + ((pA[4] + pA[5]) + (pA[6] + pA[7]));
        s2 += ((pB[0] + pB[1]) + (pB[2] + pB[3])) + ((pB[4] + pB[5]) + (pB[6] + pB[7]));

        short8 pf1, pf2;
#pragma unroll
        for (int u = 0; u < 8; ++u) { pf1[u] = (short)rbf(pA[u]); pf2[u] = (short)rbf(pB[u]); }

#pragma unroll
        for (int ot = 0; ot < 8; ++ot) {
            acc1[ot] = __builtin_amdgcn_mfma_f32_16x16x32_bf16(pf1, hf[ot], acc1[ot], 0, 0, 0);
            acc2[ot] = __builtin_amdgcn_mfma_f32_16x16x32_bf16(pf2, hf[ot], acc2[ot], 0, 0, 0);
        }
    }

    // per-row denominators (quad-reduce)
    s1 += __shfl_xor(s1, 16); s1 += __shfl_xor(s1, 32);
    s2 += __shfl_xor(s2, 16); s2 += __shfl_xor(s2, 32);
    if (lane < 16) { sbuf[w][0][lane] = s1; sbuf[w][1][lane] = s2; }

    // 2-phase accumulator combine: waves 0,1 write accb[0],accb[1];
    // waves 2,3 add into accb[0],accb[1].
    if (w < 2) {
#pragma unroll
        for (int ot = 0; ot < 8; ++ot)
#pragma unroll
            for (int r = 0; r < 4; ++r) {
                accb[w][Mlab[r]][(ot << 4) + Nlab[r]]      = acc1[ot][r];
                accb[w][16 + Mlab[r]][(ot << 4) + Nlab[r]] = acc2[ot][r];
            }
    }
    __syncthreads();
    if (w >= 2) {
#pragma unroll
        for (int ot = 0; ot < 8; ++ot)
#pragma unroll
            for (int r = 0; r < 4; ++r) {
                accb[w - 2][Mlab[r]][(ot << 4) + Nlab[r]]      += acc1[ot][r];
                accb[w - 2][16 + Mlab[r]][(ot << 4) + Nlab[r]] += acc2[ot][r];
            }
    }
    __syncthreads();

    // normalize + ELU + store: thread -> (row = tid>>3, 16-o segment)
    {
        const int row = tid >> 3;
        const int o0  = (tid & 7) << 4;
        const int g   = row >> 4;
        const int mm  = row & 15;
        const float s = (sbuf[0][g][mm] + sbuf[1][g][mm]) +
                        (sbuf[2][g][mm] + sbuf[3][g][mm]);
        const float inv = 1.0f / s;
        float* orow = out + (((size_t)gi0 + row) << 7) + o0;
#pragma unroll
        for (int v4 = 0; v4 < 4; ++v4) {
            float4 rv;
            float y;
            y = (accb[0][row][o0 + 4 * v4 + 0] + accb[1][row][o0 + 4 * v4 + 0]) * inv;
            rv.x = y > 0.f ? y : expm1f(y);
            y = (accb[0][row][o0 + 4 * v4 + 1] + accb[1][row][o0 + 4 * v4 + 1]) * inv;
            rv.y = y > 0.f ? y : expm1f(y);
            y = (accb[0][row][o0 + 4 * v4 + 2] + accb[1][row][o0 + 4 * v4 + 2]) * inv;
            rv.z = y > 0.f ? y : expm1f(y);
            y = (accb[0][row][o0 + 4 * v4 + 3] + accb[1][row][o0 + 4 * v4 + 3]) * inv;
            rv.w = y > 0.f ? y : expm1f(y);
            *(float4*)(orow + 4 * v4) = rv;
        }
    }
}

extern "C" void kernel_launch(void* const* d_in, const int* in_sizes, int n_in,
                              void* d_out, int out_size, void* d_ws, size_t ws_size,
                              hipStream_t stream) {
    const float* x   = nullptr;
    const int*   adj = nullptr;
    const float* W   = nullptr;
    const float* a   = nullptr;
    for (int i = 0; i < n_in; ++i) {
        const long s = in_sizes[i];
        if      (s == (long)BB * NN * NN)  adj = (const int*)d_in[i];
        else if (s == (long)BB * NN * FIN) x   = (const float*)d_in[i];
        else if (s == (long)FIN * FOUT)    W   = (const float*)d_in[i];
        else if (s == 2L * FOUT)           a   = (const float*)d_in[i];
    }
    if (!x)   x   = (const float*)d_in[0];
    if (!adj) adj = (const int*)d_in[1];
    if (!W)   W   = (const float*)d_in[2];
    if (!a)   a   = (const float*)d_in[3];
    float* out = (float*)d_out;

    unsigned short* wt = (unsigned short*)d_ws;            // 64 KB  W^T bf16
    unsigned short* ht = wt + 32768;                       // 4 MB   h^T bf16 [B][128][N]
    float* f1 = (float*)(ht + (size_t)BB * NN * FOUT);     // 64 KB
    float* f2 = f1 + BB * NN;                              // 64 KB

    hipLaunchKernelGGL(gat_wt, dim3(32),   dim3(256), 0, stream, W, wt);
    hipLaunchKernelGGL(gat_h3, dim3(1024), dim3(256), 0, stream, x, wt, a, ht, f1, f2);
    hipLaunchKernelGGL(gat_s4, dim3(512),  dim3(256), 0, stream, adj, ht, f1, f2, out);
}